// Round 11
// baseline (509.426 us; speedup 1.0000x reference)
//
#include <hip/hip_runtime.h>
#include <stdint.h>

#define N_NODES 100000
#define N_EDGES 1600000
#define HDIM    128
#define G_GRAPHS 64
#define NTOT (N_EDGES + N_NODES)
#define SCAN_NB ((N_NODES + 2047) / 2048)   // 49
#define PSLOTS 64
#define NSTRIPS (N_NODES / 16)              // 6250
#define NTB 512                              // transform blocks in fused kernel
#define NDB ((N_EDGES + 255) / 256)          // 6250 deg blocks

static_assert(N_NODES % 16 == 0, "tile/agg");
static_assert(SCAN_NB <= 64, "scan2 single wave");

typedef __attribute__((ext_vector_type(8))) short bf16x8;
typedef __attribute__((ext_vector_type(4))) float f32x4;
typedef __attribute__((ext_vector_type(2))) float f32x2;

__device__ __forceinline__ uint32_t f2bf(float x) {            // RNE f32->bf16
    uint32_t b = __float_as_uint(x);
    return (b + 0x7FFFu + ((b >> 16) & 1u)) >> 16;
}
__device__ __forceinline__ uint32_t pack2(float lo, float hi) {
    return f2bf(lo) | (f2bf(hi) << 16);
}

#define FXSCALE 1099511627776.0f   // 2^40

// ---- swizzle W1,W2,W3 (f32, natural) -> bf16 MFMA B-frag order in ws ----
__global__ void k_wswz(const float* __restrict__ Wa, const float* __restrict__ Wb,
                       const float* __restrict__ Wc, uint16_t* __restrict__ dst) {
    int gi = blockIdx.x * 256 + threadIdx.x;      // 0..49151
    int w = gi >> 14, idx = gi & 16383;
    const float* src = (w == 0) ? Wa : (w == 1) ? Wb : Wc;
    int k = idx >> 7, n = idx & 127;
    int kc = k >> 5, kq = (k >> 3) & 3, j = k & 7;
    int nt = n >> 4, nl = n & 15;
    dst[w * 16384 + (((kc * 8 + nt) * 64) + kq * 16 + nl) * 8 + j] = (uint16_t)f2bf(src[idx]);
}

// ---- unpack: cnt, dinv = rsqrt(deg + 1) ----
__global__ void k_dinv(const unsigned long long* __restrict__ packed,
                       int* __restrict__ cnt, float* __restrict__ dinv) {
    int i = blockIdx.x * 256 + threadIdx.x;
    if (i >= N_NODES) return;
    unsigned long long pk = packed[i];
    cnt[i] = (int)(pk >> 48);
    float deg = (float)(pk & ((1ULL << 48) - 1)) * (1.0f / FXSCALE);
    dinv[i] = 1.0f / sqrtf(deg + 1.0f);
}

// ---- exclusive scan of (cnt[i]+1), 3 phases ----
__global__ void k_scan1(const int* __restrict__ cnt, int* __restrict__ partial) {
    int tid = threadIdx.x;
    int base = blockIdx.x * 2048 + tid * 8;
    int s = 0;
#pragma unroll
    for (int j = 0; j < 8; j++) {
        int i = base + j;
        if (i < N_NODES) s += cnt[i] + 1;
    }
    for (int off = 32; off; off >>= 1) s += __shfl_down(s, off);
    __shared__ int sw[4];
    if ((tid & 63) == 0) sw[tid >> 6] = s;
    __syncthreads();
    if (tid == 0) partial[blockIdx.x] = sw[0] + sw[1] + sw[2] + sw[3];
}

__global__ void k_scan2(int* __restrict__ partial) {
    int lane = threadIdx.x;
    int v = (lane < SCAN_NB) ? partial[lane] : 0;
    int orig = v;
    for (int off = 1; off < 64; off <<= 1) {
        int u = __shfl_up(v, off);
        if (lane >= off) v += u;
    }
    if (lane < SCAN_NB) partial[lane] = v - orig;   // exclusive
}

__global__ void k_scan3(const int* __restrict__ cnt, const int* __restrict__ partial,
                        int* __restrict__ offs) {
    int tid = threadIdx.x;
    int base = blockIdx.x * 2048 + tid * 8;
    int vals[8];
    int tsum = 0;
#pragma unroll
    for (int j = 0; j < 8; j++) {
        int i = base + j;
        vals[j] = (i < N_NODES) ? cnt[i] + 1 : 0;
        tsum += vals[j];
    }
    __shared__ int s[256];
    s[tid] = tsum;
    __syncthreads();
    for (int off = 1; off < 256; off <<= 1) {
        int v = 0;
        if (tid >= off) v = s[tid - off];
        __syncthreads();
        s[tid] += v;
        __syncthreads();
    }
    int run = partial[blockIdx.x] + s[tid] - tsum;
#pragma unroll
    for (int j = 0; j < 8; j++) {
        int i = base + j;
        if (i < N_NODES) offs[i] = run;
        run += vals[j];
    }
}

// ---- fill CSR (grouped by dst) — no atomics: slot from precomputed seq ----
__global__ void k_fill(const int* __restrict__ ei, const float* __restrict__ ew,
                       const float* __restrict__ dinv, const int* __restrict__ offs,
                       const int* __restrict__ cnt, const uint16_t* __restrict__ seq,
                       int2* __restrict__ csr) {
    int e = blockIdx.x * 256 + threadIdx.x;
    if (e < N_EDGES) {
        int src = ei[e];
        int dst = ei[N_EDGES + e];
        float nrm = dinv[src] * ew[e] * dinv[dst];
        int p = offs[dst] + (int)seq[e];
        csr[p] = make_int2(src, __float_as_int(nrm));
    } else if (e < NTOT) {
        int i = e - N_EDGES;
        float d = dinv[i];
        int p = offs[i] + cnt[i];
        csr[p] = make_int2(i, __float_as_int(d * d));
    }
}

__device__ __forceinline__ bf16x8 load_row_f32(const float* p) {
    float4 a = ((const float4*)p)[0];
    float4 b = ((const float4*)p)[1];
    union { uint32_t u[4]; bf16x8 v; } c;
    c.u[0] = pack2(a.x, a.y); c.u[1] = pack2(a.z, a.w);
    c.u[2] = pack2(b.x, b.y); c.u[3] = pack2(b.z, b.w);
    return c.v;
}

// ---- transform core: t = h @ W (bf16 MFMA, fp8 out); W frags from global ----
template <int F32IN>
__device__ __forceinline__ void transform_core(int gwave, int nwaves, int tid,
                                               const void* __restrict__ hin,
                                               const bf16x8* __restrict__ Wfrag,
                                               uint32_t* __restrict__ t) {
    int lane = tid & 63;
    int quad = lane >> 4;
    int mrow = lane & 15;
    for (int strip = gwave; strip < NSTRIPS; strip += nwaves) {
        bf16x8 A0, A1, A2, A3;
        if (F32IN) {
            const float* hrow = (const float*)hin + ((size_t)(strip * 16 + mrow)) * 128 + quad * 8;
            A0 = load_row_f32(hrow);
            A1 = load_row_f32(hrow + 32);
            A2 = load_row_f32(hrow + 64);
            A3 = load_row_f32(hrow + 96);
        } else {
            const uint16_t* hrow = (const uint16_t*)hin + ((size_t)(strip * 16 + mrow)) * 128 + quad * 8;
            A0 = *(const bf16x8*)(hrow);
            A1 = *(const bf16x8*)(hrow + 32);
            A2 = *(const bf16x8*)(hrow + 64);
            A3 = *(const bf16x8*)(hrow + 96);
        }
#pragma unroll
        for (int nt = 0; nt < 8; nt++) {
            f32x4 a = {0.f, 0.f, 0.f, 0.f};
            a = __builtin_amdgcn_mfma_f32_16x16x32_bf16(A0, Wfrag[(0 * 8 + nt) * 64 + lane], a, 0, 0, 0);
            a = __builtin_amdgcn_mfma_f32_16x16x32_bf16(A1, Wfrag[(1 * 8 + nt) * 64 + lane], a, 0, 0, 0);
            a = __builtin_amdgcn_mfma_f32_16x16x32_bf16(A2, Wfrag[(2 * 8 + nt) * 64 + lane], a, 0, 0, 0);
            a = __builtin_amdgcn_mfma_f32_16x16x32_bf16(A3, Wfrag[(3 * 8 + nt) * 64 + lane], a, 0, 0, 0);
#pragma unroll
            for (int r = 0; r < 4; r++) {
                float v = a[r];
                float nb = __shfl_xor(v, 1);
                int s16 = __builtin_amdgcn_cvt_pk_fp8_f32(v, nb, 0, false); // 2x e4m3
                int hi  = __shfl_xor(s16, 2);
                if (!(lane & 3)) {
                    int orow = strip * 16 + quad * 4 + r;
                    int oc = (nt * 16 + mrow) >> 2;   // dword col 0..31
                    t[(size_t)orow * 32 + oc] = (uint32_t)(s16 & 0xffff) | ((uint32_t)hi << 16);
                }
            }
        }
    }
}

// ---- fused: deg/cnt histogram (atomic-bound) + layer-1 transform (MFMA) ----
// No LDS; VGPR capped so deg blocks keep high occupancy.
__global__ __launch_bounds__(256, 5) void k_deg_transform(
        const int* __restrict__ ei, const float* __restrict__ ew,
        unsigned long long* __restrict__ packed, uint16_t* __restrict__ seq,
        const float* __restrict__ x, const bf16x8* __restrict__ Wfrag,
        uint32_t* __restrict__ t) {
    int bi = blockIdx.x;
    int q = bi / 13;
    bool isT = ((bi % 13) == 0) && (q < NTB);
    if (isT) {
        transform_core<1>(q * 4 + (threadIdx.x >> 6), NTB * 4, threadIdx.x,
                          (const void*)x, Wfrag, t);
    } else {
        int nT = (bi + 12) / 13; if (nT > NTB) nT = NTB;
        int db = bi - nT;                       // 0..NDB-1
        int e = db * 256 + threadIdx.x;
        if (e < N_EDGES) {
            int dst = ei[N_EDGES + e];
            unsigned long long pk = (1ULL << 48) | (unsigned long long)(ew[e] * FXSCALE);
            unsigned long long old = atomicAdd(&packed[dst], pk);
            seq[e] = (uint16_t)(old >> 48);
        }
    }
}

// ---- standalone transform for layers 2-3 (LDS-free) ----
__global__ __launch_bounds__(256) void k_transform(const void* __restrict__ hin,
                                                   const bf16x8* __restrict__ Wfrag,
                                                   uint32_t* __restrict__ t) {
    transform_core<0>(blockIdx.x * 4 + (threadIdx.x >> 6), gridDim.x * 4,
                      threadIdx.x, hin, Wfrag, t);
}

// ---- aggregation: 4 nodes per wave (16 lanes each), lane holds 8 fp8 ch ----
template <int POOL>
__global__ void k_aggregate(const uint32_t* __restrict__ t, const int* __restrict__ offs,
                            const int* __restrict__ cnt, const int2* __restrict__ csr,
                            const float* __restrict__ bias, uint32_t* __restrict__ hout,
                            const float* __restrict__ lw, const int* __restrict__ batch,
                            float* __restrict__ pp) {
    int tid = threadIdx.x;
    int lane = tid & 63;
    int ql = lane & 15;
    int grp = lane & 48;                     // shfl group base
    int node = blockIdx.x * 16 + (tid >> 6) * 4 + (lane >> 4);
    int beg = offs[node];
    int num = cnt[node] + 1;
    const uint2* t2 = (const uint2*)t;
    f32x4 a0 = {0.f, 0.f, 0.f, 0.f};
    f32x4 a1 = {0.f, 0.f, 0.f, 0.f};
    for (int base = 0; base < num; base += 16) {
        int rem = num - base; if (rem > 16) rem = 16;
        int2 my = make_int2(0, 0);
        if (ql < rem) my = csr[beg + base + ql];
        int   msrc = my.x;
        float mw   = __int_as_float(my.y);
        int j = 0;
        for (; j + 8 <= rem; j += 8) {
            int s0 = __shfl(msrc, grp | (j + 0)), s1 = __shfl(msrc, grp | (j + 1));
            int s2 = __shfl(msrc, grp | (j + 2)), s3 = __shfl(msrc, grp | (j + 3));
            int s4 = __shfl(msrc, grp | (j + 4)), s5 = __shfl(msrc, grp | (j + 5));
            int s6 = __shfl(msrc, grp | (j + 6)), s7 = __shfl(msrc, grp | (j + 7));
            float w0 = __shfl(mw, grp | (j + 0)), w1 = __shfl(mw, grp | (j + 1));
            float w2 = __shfl(mw, grp | (j + 2)), w3 = __shfl(mw, grp | (j + 3));
            float w4 = __shfl(mw, grp | (j + 4)), w5 = __shfl(mw, grp | (j + 5));
            float w6 = __shfl(mw, grp | (j + 6)), w7 = __shfl(mw, grp | (j + 7));
            uint2 v0 = t2[(size_t)s0 * 16 + ql];
            uint2 v1 = t2[(size_t)s1 * 16 + ql];
            uint2 v2 = t2[(size_t)s2 * 16 + ql];
            uint2 v3 = t2[(size_t)s3 * 16 + ql];
            uint2 v4 = t2[(size_t)s4 * 16 + ql];
            uint2 v5 = t2[(size_t)s5 * 16 + ql];
            uint2 v6 = t2[(size_t)s6 * 16 + ql];
            uint2 v7 = t2[(size_t)s7 * 16 + ql];
#define ACCUM(vv, ww) { \
            f32x2 lo0 = __builtin_amdgcn_cvt_pk_f32_fp8((int)vv.x, false); \
            f32x2 hi0 = __builtin_amdgcn_cvt_pk_f32_fp8((int)vv.x, true);  \
            f32x2 lo1 = __builtin_amdgcn_cvt_pk_f32_fp8((int)vv.y, false); \
            f32x2 hi1 = __builtin_amdgcn_cvt_pk_f32_fp8((int)vv.y, true);  \
            a0.x += ww * lo0.x; a0.y += ww * lo0.y; a0.z += ww * hi0.x; a0.w += ww * hi0.y; \
            a1.x += ww * lo1.x; a1.y += ww * lo1.y; a1.z += ww * hi1.x; a1.w += ww * hi1.y; }
            ACCUM(v0, w0) ACCUM(v1, w1) ACCUM(v2, w2) ACCUM(v3, w3)
            ACCUM(v4, w4) ACCUM(v5, w5) ACCUM(v6, w6) ACCUM(v7, w7)
        }
        for (; j < rem; j++) {
            int   src = __shfl(msrc, grp | j);
            float w   = __shfl(mw, grp | j);
            uint2 v = t2[(size_t)src * 16 + ql];
            ACCUM(v, w)
        }
#undef ACCUM
    }
    float4 b0 = ((const float4*)bias)[ql * 2];
    float4 b1 = ((const float4*)bias)[ql * 2 + 1];
    a0.x = fmaxf(a0.x + b0.x, 0.f); a0.y = fmaxf(a0.y + b0.y, 0.f);
    a0.z = fmaxf(a0.z + b0.z, 0.f); a0.w = fmaxf(a0.w + b0.w, 0.f);
    a1.x = fmaxf(a1.x + b1.x, 0.f); a1.y = fmaxf(a1.y + b1.y, 0.f);
    a1.z = fmaxf(a1.z + b1.z, 0.f); a1.w = fmaxf(a1.w + b1.w, 0.f);
    if (POOL) {
        float4 w0 = ((const float4*)lw)[ql * 2];
        float4 w1 = ((const float4*)lw)[ql * 2 + 1];
        float d = a0.x * w0.x + a0.y * w0.y + a0.z * w0.z + a0.w * w0.w
                + a1.x * w1.x + a1.y * w1.y + a1.z * w1.z + a1.w * w1.w;
        for (int off = 8; off; off >>= 1) d += __shfl_down(d, off);
        if (ql == 0)
            atomicAdd(&pp[(blockIdx.x & (PSLOTS - 1)) * G_GRAPHS + batch[node]], d);
    } else {
        uint4 o;
        o.x = pack2(a0.x, a0.y);
        o.y = pack2(a0.z, a0.w);
        o.z = pack2(a1.x, a1.y);
        o.w = pack2(a1.z, a1.w);
        ((uint4*)hout)[(size_t)node * 16 + ql] = o;
    }
}

// ---- final: out[g] = (sum over slots)/cnt_g + lb ----
__global__ void k_final(const float* __restrict__ pp, const int* __restrict__ batch,
                        const float* __restrict__ lb, float* __restrict__ out) {
    int g = threadIdx.x;   // 64 threads
    float s = 0.f;
#pragma unroll
    for (int k = 0; k < PSLOTS; k++) s += pp[k * G_GRAPHS + g];
    int lo = 0, hi = N_NODES;
    while (lo < hi) { int m = (lo + hi) >> 1; if (batch[m] < g) lo = m + 1; else hi = m; }
    int beg = lo;
    hi = N_NODES;
    while (lo < hi) { int m = (lo + hi) >> 1; if (batch[m] < g + 1) lo = m + 1; else hi = m; }
    float c = fmaxf((float)(lo - beg), 1.0f);
    out[g] = s / c + lb[0];
}

extern "C" void kernel_launch(void* const* d_in, const int* in_sizes, int n_in,
                              void* d_out, int out_size, void* d_ws, size_t ws_size,
                              hipStream_t stream) {
    const float* x   = (const float*)d_in[0];
    const float* ew  = (const float*)d_in[1];
    const int*   ei  = (const int*)d_in[2];
    const int*   bat = (const int*)d_in[3];
    const float* W1  = (const float*)d_in[4];
    const float* b1  = (const float*)d_in[5];
    const float* W2  = (const float*)d_in[6];
    const float* b2  = (const float*)d_in[7];
    const float* W3  = (const float*)d_in[8];
    const float* b3  = (const float*)d_in[9];
    const float* lw  = (const float*)d_in[10];
    const float* lb  = (const float*)d_in[11];
    float* out = (float*)d_out;

    char* w = (char*)d_ws;
    size_t o = 0;
    auto carve = [&](size_t bytes) -> void* {
        void* p = w + o;
        o = (o + bytes + 255) & ~(size_t)255;
        return p;
    };
    unsigned long long* packed = (unsigned long long*)carve((size_t)N_NODES * 8);
    float* pp   = (float*)carve((size_t)PSLOTS * G_GRAPHS * 4);
    char*  zero_end = w + o;                      // packed + pp span
    int*      cnt  = (int*)     carve((size_t)N_NODES * 4);
    float*    dinv = (float*)   carve((size_t)N_NODES * 4);
    int*      offs = (int*)     carve((size_t)N_NODES * 4);
    int*      part = (int*)     carve(64 * 4);
    uint16_t* seq  = (uint16_t*)carve((size_t)N_EDGES * 2);
    int2*     csr  = (int2*)    carve((size_t)NTOT * 8);
    uint32_t* t    = (uint32_t*)carve((size_t)N_NODES * 128);      // fp8 rows, 128 B
    uint32_t* hb   = (uint32_t*)carve((size_t)N_NODES * 64 * 4);   // bf16x2
    uint16_t* wsz  = (uint16_t*)carve((size_t)3 * 16384 * 2);      // frag-order W1..W3
    (void)ws_size; (void)in_sizes; (void)n_in; (void)out_size;

    hipMemsetAsync(packed, 0, (size_t)(zero_end - (char*)packed), stream);

    k_wswz<<<192, 256, 0, stream>>>(W1, W2, W3, wsz);
    // fused: edge histogram (atomic-bound) + layer-1 transform (MFMA-bound)
    k_deg_transform<<<NTB + NDB, 256, 0, stream>>>(ei, ew, packed, seq, x,
                                                   (const bf16x8*)wsz, t);
    k_dinv<<<(N_NODES + 255) / 256, 256, 0, stream>>>(packed, cnt, dinv);
    k_scan1<<<SCAN_NB, 256, 0, stream>>>(cnt, part);
    k_scan2<<<1, 64, 0, stream>>>(part);
    k_scan3<<<SCAN_NB, 256, 0, stream>>>(cnt, part, offs);
    k_fill<<<(NTOT + 255) / 256, 256, 0, stream>>>(ei, ew, dinv, offs, cnt, seq, csr);

    k_aggregate<0><<<N_NODES / 16, 256, 0, stream>>>(t, offs, cnt, csr, b1, hb, lw, bat, pp);
    k_transform<<<512, 256, 0, stream>>>((const void*)hb, (const bf16x8*)(wsz + 16384), t);
    k_aggregate<0><<<N_NODES / 16, 256, 0, stream>>>(t, offs, cnt, csr, b2, hb, lw, bat, pp);
    k_transform<<<512, 256, 0, stream>>>((const void*)hb, (const bf16x8*)(wsz + 32768), t);
    k_aggregate<1><<<N_NODES / 16, 256, 0, stream>>>(t, offs, cnt, csr, b3, nullptr, lw, bat, pp);

    k_final<<<1, G_GRAPHS, 0, stream>>>(pp, bat, lb, out);
}

// Round 12
// 453.055 us; speedup vs baseline: 1.1244x; 1.1244x over previous
//
#include <hip/hip_runtime.h>
#include <stdint.h>

#define N_NODES 100000
#define N_EDGES 1600000
#define HDIM    128
#define G_GRAPHS 64
#define NTOT (N_EDGES + N_NODES)
#define SCAN_NB ((N_NODES + 2047) / 2048)   // 49
#define PSLOTS 64
#define NSTRIPS (N_NODES / 16)              // 6250
#define NTB 512                              // transform blocks in fused kernel
#define NDB ((N_EDGES + 255) / 256)          // 6250 deg blocks

static_assert(N_NODES % 16 == 0, "tile/agg");
static_assert(SCAN_NB <= 64, "scan2 single wave");

typedef __attribute__((ext_vector_type(8))) short bf16x8;
typedef __attribute__((ext_vector_type(4))) float f32x4;
typedef __attribute__((ext_vector_type(2))) float f32x2;

__device__ __forceinline__ uint32_t f2bf(float x) {            // RNE f32->bf16
    uint32_t b = __float_as_uint(x);
    return (b + 0x7FFFu + ((b >> 16) & 1u)) >> 16;
}
__device__ __forceinline__ uint32_t pack2(float lo, float hi) {
    return f2bf(lo) | (f2bf(hi) << 16);
}

#define FXSCALE 1099511627776.0f   // 2^40

// ---- scan1 fused with unpack: emits cnt+dinv, block-sums of (cnt+1) ----
__global__ void k_scan1(const unsigned long long* __restrict__ packed,
                        int* __restrict__ cnt, float* __restrict__ dinv,
                        int* __restrict__ partial) {
    int tid = threadIdx.x;
    int base = blockIdx.x * 2048 + tid * 8;
    int s = 0;
#pragma unroll
    for (int j = 0; j < 8; j++) {
        int i = base + j;
        if (i < N_NODES) {
            unsigned long long pk = packed[i];
            int c = (int)(pk >> 48);
            float deg = (float)(pk & ((1ULL << 48) - 1)) * (1.0f / FXSCALE);
            cnt[i] = c;
            dinv[i] = 1.0f / sqrtf(deg + 1.0f);
            s += c + 1;
        }
    }
    for (int off = 32; off; off >>= 1) s += __shfl_down(s, off);
    __shared__ int sw[4];
    if ((tid & 63) == 0) sw[tid >> 6] = s;
    __syncthreads();
    if (tid == 0) partial[blockIdx.x] = sw[0] + sw[1] + sw[2] + sw[3];
}

__global__ void k_scan2(int* __restrict__ partial) {
    int lane = threadIdx.x;
    int v = (lane < SCAN_NB) ? partial[lane] : 0;
    int orig = v;
    for (int off = 1; off < 64; off <<= 1) {
        int u = __shfl_up(v, off);
        if (lane >= off) v += u;
    }
    if (lane < SCAN_NB) partial[lane] = v - orig;   // exclusive
}

__global__ void k_scan3(const int* __restrict__ cnt, const int* __restrict__ partial,
                        int* __restrict__ offs) {
    int tid = threadIdx.x;
    int base = blockIdx.x * 2048 + tid * 8;
    int vals[8];
    int tsum = 0;
#pragma unroll
    for (int j = 0; j < 8; j++) {
        int i = base + j;
        vals[j] = (i < N_NODES) ? cnt[i] + 1 : 0;
        tsum += vals[j];
    }
    __shared__ int s[256];
    s[tid] = tsum;
    __syncthreads();
    for (int off = 1; off < 256; off <<= 1) {
        int v = 0;
        if (tid >= off) v = s[tid - off];
        __syncthreads();
        s[tid] += v;
        __syncthreads();
    }
    int run = partial[blockIdx.x] + s[tid] - tsum;
#pragma unroll
    for (int j = 0; j < 8; j++) {
        int i = base + j;
        if (i < N_NODES) offs[i] = run;
        run += vals[j];
    }
}

// ---- fill CSR (grouped by dst) — no atomics: slot from precomputed seq ----
__global__ void k_fill(const int* __restrict__ ei, const float* __restrict__ ew,
                       const float* __restrict__ dinv, const int* __restrict__ offs,
                       const int* __restrict__ cnt, const uint16_t* __restrict__ seq,
                       int2* __restrict__ csr) {
    int e = blockIdx.x * 256 + threadIdx.x;
    if (e < N_EDGES) {
        int src = ei[e];
        int dst = ei[N_EDGES + e];
        float nrm = dinv[src] * ew[e] * dinv[dst];
        int p = offs[dst] + (int)seq[e];
        csr[p] = make_int2(src, __float_as_int(nrm));
    } else if (e < NTOT) {
        int i = e - N_EDGES;
        float d = dinv[i];
        int p = offs[i] + cnt[i];
        csr[p] = make_int2(i, __float_as_int(d * d));
    }
}

__device__ __forceinline__ bf16x8 load_row_f32(const float* p) {
    float4 a = ((const float4*)p)[0];
    float4 b = ((const float4*)p)[1];
    union { uint32_t u[4]; bf16x8 v; } c;
    c.u[0] = pack2(a.x, a.y); c.u[1] = pack2(a.z, a.w);
    c.u[2] = pack2(b.x, b.y); c.u[3] = pack2(b.z, b.w);
    return c.v;
}

// ---- transform body: t = h @ W (bf16 MFMA, fp8 output), strip-strided ----
// W staged + swizzled into LDS (no bank conflicts); no VGPR cap (spill hazard).
template <int F32IN>
__device__ __forceinline__ void transform_body(int tb, int nTB, int tid,
                                               const void* __restrict__ hin,
                                               const float* __restrict__ Wg,
                                               uint32_t* __restrict__ t,
                                               uint16_t* Wf) {
    for (int idx = tid; idx < 16384; idx += 256) {
        int k = idx >> 7, n = idx & 127;
        int kc = k >> 5, kq = (k >> 3) & 3, j = k & 7;
        int nt = n >> 4, nl = n & 15;
        Wf[(((kc * 8 + nt) * 64) + kq * 16 + nl) * 8 + j] = (uint16_t)f2bf(Wg[idx]);
    }
    __syncthreads();
    const bf16x8* Wfrag = (const bf16x8*)Wf;
    int lane = tid & 63;
    int quad = lane >> 4;
    int mrow = lane & 15;
    int gwave = tb * 4 + (tid >> 6);
    int nwaves = nTB * 4;
    for (int strip = gwave; strip < NSTRIPS; strip += nwaves) {
        bf16x8 A0, A1, A2, A3;
        if (F32IN) {
            const float* hrow = (const float*)hin + ((size_t)(strip * 16 + mrow)) * 128 + quad * 8;
            A0 = load_row_f32(hrow);
            A1 = load_row_f32(hrow + 32);
            A2 = load_row_f32(hrow + 64);
            A3 = load_row_f32(hrow + 96);
        } else {
            const uint16_t* hrow = (const uint16_t*)hin + ((size_t)(strip * 16 + mrow)) * 128 + quad * 8;
            A0 = *(const bf16x8*)(hrow);
            A1 = *(const bf16x8*)(hrow + 32);
            A2 = *(const bf16x8*)(hrow + 64);
            A3 = *(const bf16x8*)(hrow + 96);
        }
        f32x4 acc[8];
#pragma unroll
        for (int nt = 0; nt < 8; nt++) {
            f32x4 a = {0.f, 0.f, 0.f, 0.f};
            a = __builtin_amdgcn_mfma_f32_16x16x32_bf16(A0, Wfrag[(0 * 8 + nt) * 64 + lane], a, 0, 0, 0);
            a = __builtin_amdgcn_mfma_f32_16x16x32_bf16(A1, Wfrag[(1 * 8 + nt) * 64 + lane], a, 0, 0, 0);
            a = __builtin_amdgcn_mfma_f32_16x16x32_bf16(A2, Wfrag[(2 * 8 + nt) * 64 + lane], a, 0, 0, 0);
            a = __builtin_amdgcn_mfma_f32_16x16x32_bf16(A3, Wfrag[(3 * 8 + nt) * 64 + lane], a, 0, 0, 0);
            acc[nt] = a;
        }
#pragma unroll
        for (int nt = 0; nt < 8; nt++) {
#pragma unroll
            for (int r = 0; r < 4; r++) {
                float v = acc[nt][r];
                float nb = __shfl_xor(v, 1);
                int s16 = __builtin_amdgcn_cvt_pk_fp8_f32(v, nb, 0, false); // 2x e4m3
                int hi  = __shfl_xor(s16, 2);
                if (!(lane & 3)) {
                    int orow = strip * 16 + quad * 4 + r;
                    int oc = (nt * 16 + mrow) >> 2;   // dword col 0..31
                    t[(size_t)orow * 32 + oc] = (uint32_t)(s16 & 0xffff) | ((uint32_t)hi << 16);
                }
            }
        }
    }
}

// ---- fused: deg/cnt histogram (atomic-bound) + layer-1 transform (MFMA) ----
__global__ __launch_bounds__(256) void k_deg_transform(
        const int* __restrict__ ei, const float* __restrict__ ew,
        unsigned long long* __restrict__ packed, uint16_t* __restrict__ seq,
        const float* __restrict__ x, const float* __restrict__ Wg,
        uint32_t* __restrict__ t) {
    __shared__ uint16_t Wf[16384];    // 32 KB (transform blocks only)
    int bi = blockIdx.x;
    int q = bi / 13;
    bool isT = ((bi % 13) == 0) && (q < NTB);
    if (isT) {
        transform_body<1>(q, NTB, threadIdx.x, (const void*)x, Wg, t, Wf);
    } else {
        int nT = (bi + 12) / 13; if (nT > NTB) nT = NTB;
        int db = bi - nT;                       // 0..NDB-1
        int e = db * 256 + threadIdx.x;
        if (e < N_EDGES) {
            int dst = ei[N_EDGES + e];
            unsigned long long pk = (1ULL << 48) | (unsigned long long)(ew[e] * FXSCALE);
            unsigned long long old = atomicAdd(&packed[dst], pk);
            seq[e] = (uint16_t)(old >> 48);
        }
    }
}

// ---- standalone transform for layers 2-3 ----
__global__ __launch_bounds__(256) void k_transform(const void* __restrict__ hin,
                                                   const float* __restrict__ Wg,
                                                   uint32_t* __restrict__ t) {
    __shared__ uint16_t Wf[16384];
    transform_body<0>(blockIdx.x, gridDim.x, threadIdx.x, hin, Wg, t, Wf);
}

// ---- aggregation: 4 nodes per wave (16 lanes each), lane holds 8 fp8 ch ----
template <int POOL>
__global__ void k_aggregate(const uint32_t* __restrict__ t, const int* __restrict__ offs,
                            const int* __restrict__ cnt, const int2* __restrict__ csr,
                            const float* __restrict__ bias, uint32_t* __restrict__ hout,
                            const float* __restrict__ lw, const int* __restrict__ batch,
                            float* __restrict__ pp) {
    int tid = threadIdx.x;
    int lane = tid & 63;
    int ql = lane & 15;
    int grp = lane & 48;                     // shfl group base
    int node = blockIdx.x * 16 + (tid >> 6) * 4 + (lane >> 4);
    int beg = offs[node];
    int num = cnt[node] + 1;
    const uint2* t2 = (const uint2*)t;
    f32x4 a0 = {0.f, 0.f, 0.f, 0.f};
    f32x4 a1 = {0.f, 0.f, 0.f, 0.f};
    for (int base = 0; base < num; base += 16) {
        int rem = num - base; if (rem > 16) rem = 16;
        int2 my = make_int2(0, 0);
        if (ql < rem) my = csr[beg + base + ql];
        int   msrc = my.x;
        float mw   = __int_as_float(my.y);
        int j = 0;
        for (; j + 8 <= rem; j += 8) {
            int s0 = __shfl(msrc, grp | (j + 0)), s1 = __shfl(msrc, grp | (j + 1));
            int s2 = __shfl(msrc, grp | (j + 2)), s3 = __shfl(msrc, grp | (j + 3));
            int s4 = __shfl(msrc, grp | (j + 4)), s5 = __shfl(msrc, grp | (j + 5));
            int s6 = __shfl(msrc, grp | (j + 6)), s7 = __shfl(msrc, grp | (j + 7));
            float w0 = __shfl(mw, grp | (j + 0)), w1 = __shfl(mw, grp | (j + 1));
            float w2 = __shfl(mw, grp | (j + 2)), w3 = __shfl(mw, grp | (j + 3));
            float w4 = __shfl(mw, grp | (j + 4)), w5 = __shfl(mw, grp | (j + 5));
            float w6 = __shfl(mw, grp | (j + 6)), w7 = __shfl(mw, grp | (j + 7));
            uint2 v0 = t2[(size_t)s0 * 16 + ql];
            uint2 v1 = t2[(size_t)s1 * 16 + ql];
            uint2 v2 = t2[(size_t)s2 * 16 + ql];
            uint2 v3 = t2[(size_t)s3 * 16 + ql];
            uint2 v4 = t2[(size_t)s4 * 16 + ql];
            uint2 v5 = t2[(size_t)s5 * 16 + ql];
            uint2 v6 = t2[(size_t)s6 * 16 + ql];
            uint2 v7 = t2[(size_t)s7 * 16 + ql];
#define ACCUM(vv, ww) { \
            f32x2 lo0 = __builtin_amdgcn_cvt_pk_f32_fp8((int)vv.x, false); \
            f32x2 hi0 = __builtin_amdgcn_cvt_pk_f32_fp8((int)vv.x, true);  \
            f32x2 lo1 = __builtin_amdgcn_cvt_pk_f32_fp8((int)vv.y, false); \
            f32x2 hi1 = __builtin_amdgcn_cvt_pk_f32_fp8((int)vv.y, true);  \
            a0.x += ww * lo0.x; a0.y += ww * lo0.y; a0.z += ww * hi0.x; a0.w += ww * hi0.y; \
            a1.x += ww * lo1.x; a1.y += ww * lo1.y; a1.z += ww * hi1.x; a1.w += ww * hi1.y; }
            ACCUM(v0, w0) ACCUM(v1, w1) ACCUM(v2, w2) ACCUM(v3, w3)
            ACCUM(v4, w4) ACCUM(v5, w5) ACCUM(v6, w6) ACCUM(v7, w7)
        }
        for (; j < rem; j++) {
            int   src = __shfl(msrc, grp | j);
            float w   = __shfl(mw, grp | j);
            uint2 v = t2[(size_t)src * 16 + ql];
            ACCUM(v, w)
        }
#undef ACCUM
    }
    float4 b0 = ((const float4*)bias)[ql * 2];
    float4 b1 = ((const float4*)bias)[ql * 2 + 1];
    a0.x = fmaxf(a0.x + b0.x, 0.f); a0.y = fmaxf(a0.y + b0.y, 0.f);
    a0.z = fmaxf(a0.z + b0.z, 0.f); a0.w = fmaxf(a0.w + b0.w, 0.f);
    a1.x = fmaxf(a1.x + b1.x, 0.f); a1.y = fmaxf(a1.y + b1.y, 0.f);
    a1.z = fmaxf(a1.z + b1.z, 0.f); a1.w = fmaxf(a1.w + b1.w, 0.f);
    if (POOL) {
        float4 w0 = ((const float4*)lw)[ql * 2];
        float4 w1 = ((const float4*)lw)[ql * 2 + 1];
        float d = a0.x * w0.x + a0.y * w0.y + a0.z * w0.z + a0.w * w0.w
                + a1.x * w1.x + a1.y * w1.y + a1.z * w1.z + a1.w * w1.w;
        for (int off = 8; off; off >>= 1) d += __shfl_down(d, off);
        if (ql == 0)
            atomicAdd(&pp[(blockIdx.x & (PSLOTS - 1)) * G_GRAPHS + batch[node]], d);
    } else {
        uint4 o;
        o.x = pack2(a0.x, a0.y);
        o.y = pack2(a0.z, a0.w);
        o.z = pack2(a1.x, a1.y);
        o.w = pack2(a1.z, a1.w);
        ((uint4*)hout)[(size_t)node * 16 + ql] = o;
    }
}

// ---- final: out[g] = (sum over slots)/cnt_g + lb ----
__global__ void k_final(const float* __restrict__ pp, const int* __restrict__ batch,
                        const float* __restrict__ lb, float* __restrict__ out) {
    int g = threadIdx.x;   // 64 threads
    float s = 0.f;
#pragma unroll
    for (int k = 0; k < PSLOTS; k++) s += pp[k * G_GRAPHS + g];
    int lo = 0, hi = N_NODES;
    while (lo < hi) { int m = (lo + hi) >> 1; if (batch[m] < g) lo = m + 1; else hi = m; }
    int beg = lo;
    hi = N_NODES;
    while (lo < hi) { int m = (lo + hi) >> 1; if (batch[m] < g + 1) lo = m + 1; else hi = m; }
    float c = fmaxf((float)(lo - beg), 1.0f);
    out[g] = s / c + lb[0];
}

extern "C" void kernel_launch(void* const* d_in, const int* in_sizes, int n_in,
                              void* d_out, int out_size, void* d_ws, size_t ws_size,
                              hipStream_t stream) {
    const float* x   = (const float*)d_in[0];
    const float* ew  = (const float*)d_in[1];
    const int*   ei  = (const int*)d_in[2];
    const int*   bat = (const int*)d_in[3];
    const float* W1  = (const float*)d_in[4];
    const float* b1  = (const float*)d_in[5];
    const float* W2  = (const float*)d_in[6];
    const float* b2  = (const float*)d_in[7];
    const float* W3  = (const float*)d_in[8];
    const float* b3  = (const float*)d_in[9];
    const float* lw  = (const float*)d_in[10];
    const float* lb  = (const float*)d_in[11];
    float* out = (float*)d_out;

    char* w = (char*)d_ws;
    size_t o = 0;
    auto carve = [&](size_t bytes) -> void* {
        void* p = w + o;
        o = (o + bytes + 255) & ~(size_t)255;
        return p;
    };
    unsigned long long* packed = (unsigned long long*)carve((size_t)N_NODES * 8);
    float* pp   = (float*)carve((size_t)PSLOTS * G_GRAPHS * 4);
    char*  zero_end = w + o;                      // packed + pp span
    int*      cnt  = (int*)     carve((size_t)N_NODES * 4);
    float*    dinv = (float*)   carve((size_t)N_NODES * 4);
    int*      offs = (int*)     carve((size_t)N_NODES * 4);
    int*      part = (int*)     carve(64 * 4);
    uint16_t* seq  = (uint16_t*)carve((size_t)N_EDGES * 2);
    int2*     csr  = (int2*)    carve((size_t)NTOT * 8);
    uint32_t* t    = (uint32_t*)carve((size_t)N_NODES * 128);      // fp8 rows, 128 B
    uint32_t* hb   = (uint32_t*)carve((size_t)N_NODES * 64 * 4);   // bf16x2
    (void)ws_size; (void)in_sizes; (void)n_in; (void)out_size;

    hipMemsetAsync(packed, 0, (size_t)(zero_end - (char*)packed), stream);

    // fused: edge histogram (atomic-bound) + layer-1 transform (MFMA-bound)
    k_deg_transform<<<NTB + NDB, 256, 0, stream>>>(ei, ew, packed, seq, x, W1, t);
    k_scan1<<<SCAN_NB, 256, 0, stream>>>(packed, cnt, dinv, part);
    k_scan2<<<1, 64, 0, stream>>>(part);
    k_scan3<<<SCAN_NB, 256, 0, stream>>>(cnt, part, offs);
    k_fill<<<(NTOT + 255) / 256, 256, 0, stream>>>(ei, ew, dinv, offs, cnt, seq, csr);

    k_aggregate<0><<<N_NODES / 16, 256, 0, stream>>>(t, offs, cnt, csr, b1, hb, lw, bat, pp);
    k_transform<<<512, 256, 0, stream>>>((const void*)hb, W2, t);
    k_aggregate<0><<<N_NODES / 16, 256, 0, stream>>>(t, offs, cnt, csr, b2, hb, lw, bat, pp);
    k_transform<<<512, 256, 0, stream>>>((const void*)hb, W3, t);
    k_aggregate<1><<<N_NODES / 16, 256, 0, stream>>>(t, offs, cnt, csr, b3, nullptr, lw, bat, pp);

    k_final<<<1, G_GRAPHS, 0, stream>>>(pp, bat, lb, out);
}

// Round 13
// 420.331 us; speedup vs baseline: 1.2120x; 1.0779x over previous
//
#include <hip/hip_runtime.h>
#include <stdint.h>

#define N_NODES 100000
#define N_EDGES 1600000
#define HDIM    128
#define G_GRAPHS 64
#define NTOT (N_EDGES + N_NODES)
#define SCAN_NB ((N_NODES + 2047) / 2048)   // 49
#define PSLOTS 64
#define NSTRIPS (N_NODES / 16)              // 6250
#define NTB 512                              // transform blocks in fused kernel
#define NDB ((N_EDGES + 255) / 256)          // 6250 deg blocks

static_assert(N_NODES % 16 == 0, "tile/agg");
static_assert(SCAN_NB <= 64, "scan fixup single wave");

typedef __attribute__((ext_vector_type(8))) short bf16x8;
typedef __attribute__((ext_vector_type(4))) float f32x4;
typedef __attribute__((ext_vector_type(2))) float f32x2;

__device__ __forceinline__ uint32_t f2bf(float x) {            // RNE f32->bf16
    uint32_t b = __float_as_uint(x);
    return (b + 0x7FFFu + ((b >> 16) & 1u)) >> 16;
}
__device__ __forceinline__ uint32_t pack2(float lo, float hi) {
    return f2bf(lo) | (f2bf(hi) << 16);
}

#define FXSCALE 1099511627776.0f   // 2^40

// ---- swizzle W2,W3 (f32 natural) -> bf16 MFMA B-frag order in ws ----
__global__ void k_wswz(const float* __restrict__ Wb, const float* __restrict__ Wc,
                       uint16_t* __restrict__ dst) {
    int gi = blockIdx.x * 256 + threadIdx.x;      // 0..32767
    int w = gi >> 14, idx = gi & 16383;
    const float* src = (w == 0) ? Wb : Wc;
    int k = idx >> 7, n = idx & 127;
    int kc = k >> 5, kq = (k >> 3) & 3, j = k & 7;
    int nt = n >> 4, nl = n & 15;
    dst[w * 16384 + (((kc * 8 + nt) * 64) + kq * 16 + nl) * 8 + j] = (uint16_t)f2bf(src[idx]);
}

// ---- scan1 fused with unpack: emits cnt+dinv, block-sums of (cnt+1) ----
__global__ void k_scan1(const unsigned long long* __restrict__ packed,
                        int* __restrict__ cnt, float* __restrict__ dinv,
                        int* __restrict__ partial) {
    int tid = threadIdx.x;
    int base = blockIdx.x * 2048 + tid * 8;
    int s = 0;
#pragma unroll
    for (int j = 0; j < 8; j++) {
        int i = base + j;
        if (i < N_NODES) {
            unsigned long long pk = packed[i];
            int c = (int)(pk >> 48);
            float deg = (float)(pk & ((1ULL << 48) - 1)) * (1.0f / FXSCALE);
            cnt[i] = c;
            dinv[i] = 1.0f / sqrtf(deg + 1.0f);
            s += c + 1;
        }
    }
    for (int off = 32; off; off >>= 1) s += __shfl_down(s, off);
    __shared__ int sw[4];
    if ((tid & 63) == 0) sw[tid >> 6] = s;
    __syncthreads();
    if (tid == 0) partial[blockIdx.x] = sw[0] + sw[1] + sw[2] + sw[3];
}

// ---- scan3 with inlined scan2: wave 0 re-scans the 49 partials locally ----
__global__ void k_scan3(const int* __restrict__ cnt, const int* __restrict__ partial,
                        int* __restrict__ offs) {
    __shared__ int bbase[SCAN_NB];
    int tid = threadIdx.x;
    if (tid < 64) {
        int v = (tid < SCAN_NB) ? partial[tid] : 0;
        int orig = v;
        for (int off = 1; off < 64; off <<= 1) {
            int u = __shfl_up(v, off);
            if (tid >= off) v += u;
        }
        if (tid < SCAN_NB) bbase[tid] = v - orig;   // exclusive
    }
    int base = blockIdx.x * 2048 + tid * 8;
    int vals[8];
    int tsum = 0;
#pragma unroll
    for (int j = 0; j < 8; j++) {
        int i = base + j;
        vals[j] = (i < N_NODES) ? cnt[i] + 1 : 0;
        tsum += vals[j];
    }
    __shared__ int s[256];
    s[tid] = tsum;
    __syncthreads();
    for (int off = 1; off < 256; off <<= 1) {
        int v = 0;
        if (tid >= off) v = s[tid - off];
        __syncthreads();
        s[tid] += v;
        __syncthreads();
    }
    int run = bbase[blockIdx.x] + s[tid] - tsum;
#pragma unroll
    for (int j = 0; j < 8; j++) {
        int i = base + j;
        if (i < N_NODES) offs[i] = run;
        run += vals[j];
    }
}

// ---- fill CSR (grouped by dst) — no atomics: slot from precomputed seq ----
__global__ void k_fill(const int* __restrict__ ei, const float* __restrict__ ew,
                       const float* __restrict__ dinv, const int* __restrict__ offs,
                       const int* __restrict__ cnt, const uint16_t* __restrict__ seq,
                       int2* __restrict__ csr) {
    int e = blockIdx.x * 256 + threadIdx.x;
    if (e < N_EDGES) {
        int src = ei[e];
        int dst = ei[N_EDGES + e];
        float nrm = dinv[src] * ew[e] * dinv[dst];
        int p = offs[dst] + (int)seq[e];
        csr[p] = make_int2(src, __float_as_int(nrm));
    } else if (e < NTOT) {
        int i = e - N_EDGES;
        float d = dinv[i];
        int p = offs[i] + cnt[i];
        csr[p] = make_int2(i, __float_as_int(d * d));
    }
}

__device__ __forceinline__ bf16x8 load_row_f32(const float* p) {
    float4 a = ((const float4*)p)[0];
    float4 b = ((const float4*)p)[1];
    union { uint32_t u[4]; bf16x8 v; } c;
    c.u[0] = pack2(a.x, a.y); c.u[1] = pack2(a.z, a.w);
    c.u[2] = pack2(b.x, b.y); c.u[3] = pack2(b.z, b.w);
    return c.v;
}

// ---- layer-1 transform body (x f32 in, fp8 out), W staged in LDS ----
__device__ __forceinline__ void transform_body_l1(int tb, int nTB, int tid,
                                                  const float* __restrict__ hin,
                                                  const float* __restrict__ Wg,
                                                  uint32_t* __restrict__ t,
                                                  uint16_t* Wf) {
    for (int idx = tid; idx < 16384; idx += 256) {
        int k = idx >> 7, n = idx & 127;
        int kc = k >> 5, kq = (k >> 3) & 3, j = k & 7;
        int nt = n >> 4, nl = n & 15;
        Wf[(((kc * 8 + nt) * 64) + kq * 16 + nl) * 8 + j] = (uint16_t)f2bf(Wg[idx]);
    }
    __syncthreads();
    const bf16x8* Wfrag = (const bf16x8*)Wf;
    int lane = tid & 63;
    int quad = lane >> 4;
    int mrow = lane & 15;
    int gwave = tb * 4 + (tid >> 6);
    int nwaves = nTB * 4;
    for (int strip = gwave; strip < NSTRIPS; strip += nwaves) {
        const float* hrow = hin + ((size_t)(strip * 16 + mrow)) * 128 + quad * 8;
        bf16x8 A0 = load_row_f32(hrow);
        bf16x8 A1 = load_row_f32(hrow + 32);
        bf16x8 A2 = load_row_f32(hrow + 64);
        bf16x8 A3 = load_row_f32(hrow + 96);
        f32x4 acc[8];
#pragma unroll
        for (int nt = 0; nt < 8; nt++) {
            f32x4 a = {0.f, 0.f, 0.f, 0.f};
            a = __builtin_amdgcn_mfma_f32_16x16x32_bf16(A0, Wfrag[(0 * 8 + nt) * 64 + lane], a, 0, 0, 0);
            a = __builtin_amdgcn_mfma_f32_16x16x32_bf16(A1, Wfrag[(1 * 8 + nt) * 64 + lane], a, 0, 0, 0);
            a = __builtin_amdgcn_mfma_f32_16x16x32_bf16(A2, Wfrag[(2 * 8 + nt) * 64 + lane], a, 0, 0, 0);
            a = __builtin_amdgcn_mfma_f32_16x16x32_bf16(A3, Wfrag[(3 * 8 + nt) * 64 + lane], a, 0, 0, 0);
            acc[nt] = a;
        }
#pragma unroll
        for (int nt = 0; nt < 8; nt++) {
#pragma unroll
            for (int r = 0; r < 4; r++) {
                float v = acc[nt][r];
                float nb = __shfl_xor(v, 1);
                int s16 = __builtin_amdgcn_cvt_pk_fp8_f32(v, nb, 0, false); // 2x e4m3
                int hi  = __shfl_xor(s16, 2);
                if (!(lane & 3)) {
                    int orow = strip * 16 + quad * 4 + r;
                    int oc = (nt * 16 + mrow) >> 2;   // dword col 0..31
                    t[(size_t)orow * 32 + oc] = (uint32_t)(s16 & 0xffff) | ((uint32_t)hi << 16);
                }
            }
        }
    }
}

// ---- fused: deg/cnt histogram (atomic-bound) + layer-1 transform (MFMA) ----
__global__ __launch_bounds__(256) void k_deg_transform(
        const int* __restrict__ ei, const float* __restrict__ ew,
        unsigned long long* __restrict__ packed, uint16_t* __restrict__ seq,
        const float* __restrict__ x, const float* __restrict__ Wg,
        uint32_t* __restrict__ t) {
    __shared__ uint16_t Wf[16384];    // 32 KB (transform blocks only)
    int bi = blockIdx.x;
    int q = bi / 13;
    bool isT = ((bi % 13) == 0) && (q < NTB);
    if (isT) {
        transform_body_l1(q, NTB, threadIdx.x, x, Wg, t, Wf);
    } else {
        int nT = (bi + 12) / 13; if (nT > NTB) nT = NTB;
        int db = bi - nT;                       // 0..NDB-1
        int e = db * 256 + threadIdx.x;
        if (e < N_EDGES) {
            int dst = ei[N_EDGES + e];
            unsigned long long pk = (1ULL << 48) | (unsigned long long)(ew[e] * FXSCALE);
            unsigned long long old = atomicAdd(&packed[dst], pk);
            seq[e] = (uint16_t)(old >> 48);
        }
    }
}

// ---- fused aggregate + transform: one block = 16 nodes = one MFMA strip ----
// Phase 1: 4 nodes/wave fp8 gather-aggregate -> bf16 h-tile in LDS (4 KB,
//          slot-rotated). Phase 2: block's 4 waves run the strip MFMA
//          (2 nt-tiles each), B-frags from pre-swizzled global W, fp8 t out.
__global__ __launch_bounds__(256) void k_agg_tr(
        const uint32_t* __restrict__ tin, const int* __restrict__ offs,
        const int* __restrict__ cnt, const int2* __restrict__ csr,
        const float* __restrict__ bias, const bf16x8* __restrict__ Wfrag,
        uint32_t* __restrict__ tout) {
    __shared__ uint32_t ht[16 * 16 * 4];     // [m][slot][4 dwords] = 4 KB
    int tid = threadIdx.x;
    int lane = tid & 63;
    int ql = lane & 15;
    int grp = lane & 48;
    int row = (tid >> 6) * 4 + (lane >> 4);  // local node 0..15
    int node = blockIdx.x * 16 + row;
    int beg = offs[node];
    int num = cnt[node] + 1;
    const uint2* t2 = (const uint2*)tin;
    f32x4 a0 = {0.f, 0.f, 0.f, 0.f};
    f32x4 a1 = {0.f, 0.f, 0.f, 0.f};
    for (int base = 0; base < num; base += 16) {
        int rem = num - base; if (rem > 16) rem = 16;
        int2 my = make_int2(0, 0);
        if (ql < rem) my = csr[beg + base + ql];
        int   msrc = my.x;
        float mw   = __int_as_float(my.y);
        int j = 0;
        for (; j + 8 <= rem; j += 8) {
            int s0 = __shfl(msrc, grp | (j + 0)), s1 = __shfl(msrc, grp | (j + 1));
            int s2 = __shfl(msrc, grp | (j + 2)), s3 = __shfl(msrc, grp | (j + 3));
            int s4 = __shfl(msrc, grp | (j + 4)), s5 = __shfl(msrc, grp | (j + 5));
            int s6 = __shfl(msrc, grp | (j + 6)), s7 = __shfl(msrc, grp | (j + 7));
            float w0 = __shfl(mw, grp | (j + 0)), w1 = __shfl(mw, grp | (j + 1));
            float w2 = __shfl(mw, grp | (j + 2)), w3 = __shfl(mw, grp | (j + 3));
            float w4 = __shfl(mw, grp | (j + 4)), w5 = __shfl(mw, grp | (j + 5));
            float w6 = __shfl(mw, grp | (j + 6)), w7 = __shfl(mw, grp | (j + 7));
            uint2 v0 = t2[(size_t)s0 * 16 + ql];
            uint2 v1 = t2[(size_t)s1 * 16 + ql];
            uint2 v2 = t2[(size_t)s2 * 16 + ql];
            uint2 v3 = t2[(size_t)s3 * 16 + ql];
            uint2 v4 = t2[(size_t)s4 * 16 + ql];
            uint2 v5 = t2[(size_t)s5 * 16 + ql];
            uint2 v6 = t2[(size_t)s6 * 16 + ql];
            uint2 v7 = t2[(size_t)s7 * 16 + ql];
#define ACCUM(vv, ww) { \
            f32x2 lo0 = __builtin_amdgcn_cvt_pk_f32_fp8((int)vv.x, false); \
            f32x2 hi0 = __builtin_amdgcn_cvt_pk_f32_fp8((int)vv.x, true);  \
            f32x2 lo1 = __builtin_amdgcn_cvt_pk_f32_fp8((int)vv.y, false); \
            f32x2 hi1 = __builtin_amdgcn_cvt_pk_f32_fp8((int)vv.y, true);  \
            a0.x += ww * lo0.x; a0.y += ww * lo0.y; a0.z += ww * hi0.x; a0.w += ww * hi0.y; \
            a1.x += ww * lo1.x; a1.y += ww * lo1.y; a1.z += ww * hi1.x; a1.w += ww * hi1.y; }
            ACCUM(v0, w0) ACCUM(v1, w1) ACCUM(v2, w2) ACCUM(v3, w3)
            ACCUM(v4, w4) ACCUM(v5, w5) ACCUM(v6, w6) ACCUM(v7, w7)
        }
        for (; j < rem; j++) {
            int   src = __shfl(msrc, grp | j);
            float w   = __shfl(mw, grp | j);
            uint2 v = t2[(size_t)src * 16 + ql];
            ACCUM(v, w)
        }
#undef ACCUM
    }
    float4 b0 = ((const float4*)bias)[ql * 2];
    float4 b1 = ((const float4*)bias)[ql * 2 + 1];
    a0.x = fmaxf(a0.x + b0.x, 0.f); a0.y = fmaxf(a0.y + b0.y, 0.f);
    a0.z = fmaxf(a0.z + b0.z, 0.f); a0.w = fmaxf(a0.w + b0.w, 0.f);
    a1.x = fmaxf(a1.x + b1.x, 0.f); a1.y = fmaxf(a1.y + b1.y, 0.f);
    a1.z = fmaxf(a1.z + b1.z, 0.f); a1.w = fmaxf(a1.w + b1.w, 0.f);
    {
        int slot = (ql + row) & 15;              // rotate to spread LDS banks
        uint32_t* dst = &ht[(row * 16 + slot) * 4];
        dst[0] = pack2(a0.x, a0.y);
        dst[1] = pack2(a0.z, a0.w);
        dst[2] = pack2(a1.x, a1.y);
        dst[3] = pack2(a1.z, a1.w);
    }
    __syncthreads();
    // ---- transform phase: wave w handles nt = 2w, 2w+1 ----
    int quad = lane >> 4;
    int m = lane & 15;
    int wid = tid >> 6;
    bf16x8 A[4];
#pragma unroll
    for (int c = 0; c < 4; c++) {
        int sl = (c * 4 + quad + m) & 15;
        A[c] = *(const bf16x8*)&ht[(m * 16 + sl) * 4];
    }
    int strip = blockIdx.x;
#pragma unroll
    for (int u = 0; u < 2; u++) {
        int nt = wid * 2 + u;
        f32x4 a = {0.f, 0.f, 0.f, 0.f};
        a = __builtin_amdgcn_mfma_f32_16x16x32_bf16(A[0], Wfrag[(0 * 8 + nt) * 64 + lane], a, 0, 0, 0);
        a = __builtin_amdgcn_mfma_f32_16x16x32_bf16(A[1], Wfrag[(1 * 8 + nt) * 64 + lane], a, 0, 0, 0);
        a = __builtin_amdgcn_mfma_f32_16x16x32_bf16(A[2], Wfrag[(2 * 8 + nt) * 64 + lane], a, 0, 0, 0);
        a = __builtin_amdgcn_mfma_f32_16x16x32_bf16(A[3], Wfrag[(3 * 8 + nt) * 64 + lane], a, 0, 0, 0);
#pragma unroll
        for (int r = 0; r < 4; r++) {
            float v = a[r];
            float nb = __shfl_xor(v, 1);
            int s16 = __builtin_amdgcn_cvt_pk_fp8_f32(v, nb, 0, false);
            int hi  = __shfl_xor(s16, 2);
            if (!(lane & 3)) {
                int orow = strip * 16 + quad * 4 + r;
                int oc = (nt * 16 + m) >> 2;
                tout[(size_t)orow * 32 + oc] = (uint32_t)(s16 & 0xffff) | ((uint32_t)hi << 16);
            }
        }
    }
}

// ---- last layer: aggregation + fused pool (4 nodes/wave) ----
__global__ void k_agg_pool(const uint32_t* __restrict__ t, const int* __restrict__ offs,
                           const int* __restrict__ cnt, const int2* __restrict__ csr,
                           const float* __restrict__ bias, const float* __restrict__ lw,
                           const int* __restrict__ batch, float* __restrict__ pp) {
    int tid = threadIdx.x;
    int lane = tid & 63;
    int ql = lane & 15;
    int grp = lane & 48;
    int node = blockIdx.x * 16 + (tid >> 6) * 4 + (lane >> 4);
    int beg = offs[node];
    int num = cnt[node] + 1;
    const uint2* t2 = (const uint2*)t;
    f32x4 a0 = {0.f, 0.f, 0.f, 0.f};
    f32x4 a1 = {0.f, 0.f, 0.f, 0.f};
    for (int base = 0; base < num; base += 16) {
        int rem = num - base; if (rem > 16) rem = 16;
        int2 my = make_int2(0, 0);
        if (ql < rem) my = csr[beg + base + ql];
        int   msrc = my.x;
        float mw   = __int_as_float(my.y);
        int j = 0;
        for (; j + 8 <= rem; j += 8) {
            int s0 = __shfl(msrc, grp | (j + 0)), s1 = __shfl(msrc, grp | (j + 1));
            int s2 = __shfl(msrc, grp | (j + 2)), s3 = __shfl(msrc, grp | (j + 3));
            int s4 = __shfl(msrc, grp | (j + 4)), s5 = __shfl(msrc, grp | (j + 5));
            int s6 = __shfl(msrc, grp | (j + 6)), s7 = __shfl(msrc, grp | (j + 7));
            float w0 = __shfl(mw, grp | (j + 0)), w1 = __shfl(mw, grp | (j + 1));
            float w2 = __shfl(mw, grp | (j + 2)), w3 = __shfl(mw, grp | (j + 3));
            float w4 = __shfl(mw, grp | (j + 4)), w5 = __shfl(mw, grp | (j + 5));
            float w6 = __shfl(mw, grp | (j + 6)), w7 = __shfl(mw, grp | (j + 7));
            uint2 v0 = t2[(size_t)s0 * 16 + ql];
            uint2 v1 = t2[(size_t)s1 * 16 + ql];
            uint2 v2 = t2[(size_t)s2 * 16 + ql];
            uint2 v3 = t2[(size_t)s3 * 16 + ql];
            uint2 v4 = t2[(size_t)s4 * 16 + ql];
            uint2 v5 = t2[(size_t)s5 * 16 + ql];
            uint2 v6 = t2[(size_t)s6 * 16 + ql];
            uint2 v7 = t2[(size_t)s7 * 16 + ql];
#define ACCUM(vv, ww) { \
            f32x2 lo0 = __builtin_amdgcn_cvt_pk_f32_fp8((int)vv.x, false); \
            f32x2 hi0 = __builtin_amdgcn_cvt_pk_f32_fp8((int)vv.x, true);  \
            f32x2 lo1 = __builtin_amdgcn_cvt_pk_f32_fp8((int)vv.y, false); \
            f32x2 hi1 = __builtin_amdgcn_cvt_pk_f32_fp8((int)vv.y, true);  \
            a0.x += ww * lo0.x; a0.y += ww * lo0.y; a0.z += ww * hi0.x; a0.w += ww * hi0.y; \
            a1.x += ww * lo1.x; a1.y += ww * lo1.y; a1.z += ww * hi1.x; a1.w += ww * hi1.y; }
            ACCUM(v0, w0) ACCUM(v1, w1) ACCUM(v2, w2) ACCUM(v3, w3)
            ACCUM(v4, w4) ACCUM(v5, w5) ACCUM(v6, w6) ACCUM(v7, w7)
        }
        for (; j < rem; j++) {
            int   src = __shfl(msrc, grp | j);
            float w   = __shfl(mw, grp | j);
            uint2 v = t2[(size_t)src * 16 + ql];
            ACCUM(v, w)
        }
#undef ACCUM
    }
    float4 b0 = ((const float4*)bias)[ql * 2];
    float4 b1 = ((const float4*)bias)[ql * 2 + 1];
    a0.x = fmaxf(a0.x + b0.x, 0.f); a0.y = fmaxf(a0.y + b0.y, 0.f);
    a0.z = fmaxf(a0.z + b0.z, 0.f); a0.w = fmaxf(a0.w + b0.w, 0.f);
    a1.x = fmaxf(a1.x + b1.x, 0.f); a1.y = fmaxf(a1.y + b1.y, 0.f);
    a1.z = fmaxf(a1.z + b1.z, 0.f); a1.w = fmaxf(a1.w + b1.w, 0.f);
    float4 w0 = ((const float4*)lw)[ql * 2];
    float4 w1 = ((const float4*)lw)[ql * 2 + 1];
    float d = a0.x * w0.x + a0.y * w0.y + a0.z * w0.z + a0.w * w0.w
            + a1.x * w1.x + a1.y * w1.y + a1.z * w1.z + a1.w * w1.w;
    for (int off = 8; off; off >>= 1) d += __shfl_down(d, off);
    if (ql == 0)
        atomicAdd(&pp[(blockIdx.x & (PSLOTS - 1)) * G_GRAPHS + batch[node]], d);
}

// ---- final: out[g] = (sum over slots)/cnt_g + lb ----
__global__ void k_final(const float* __restrict__ pp, const int* __restrict__ batch,
                        const float* __restrict__ lb, float* __restrict__ out) {
    int g = threadIdx.x;   // 64 threads
    float s = 0.f;
#pragma unroll
    for (int k = 0; k < PSLOTS; k++) s += pp[k * G_GRAPHS + g];
    int lo = 0, hi = N_NODES;
    while (lo < hi) { int m = (lo + hi) >> 1; if (batch[m] < g) lo = m + 1; else hi = m; }
    int beg = lo;
    hi = N_NODES;
    while (lo < hi) { int m = (lo + hi) >> 1; if (batch[m] < g + 1) lo = m + 1; else hi = m; }
    float c = fmaxf((float)(lo - beg), 1.0f);
    out[g] = s / c + lb[0];
}

extern "C" void kernel_launch(void* const* d_in, const int* in_sizes, int n_in,
                              void* d_out, int out_size, void* d_ws, size_t ws_size,
                              hipStream_t stream) {
    const float* x   = (const float*)d_in[0];
    const float* ew  = (const float*)d_in[1];
    const int*   ei  = (const int*)d_in[2];
    const int*   bat = (const int*)d_in[3];
    const float* W1  = (const float*)d_in[4];
    const float* b1  = (const float*)d_in[5];
    const float* W2  = (const float*)d_in[6];
    const float* b2  = (const float*)d_in[7];
    const float* W3  = (const float*)d_in[8];
    const float* b3  = (const float*)d_in[9];
    const float* lw  = (const float*)d_in[10];
    const float* lb  = (const float*)d_in[11];
    float* out = (float*)d_out;

    char* w = (char*)d_ws;
    size_t o = 0;
    auto carve = [&](size_t bytes) -> void* {
        void* p = w + o;
        o = (o + bytes + 255) & ~(size_t)255;
        return p;
    };
    unsigned long long* packed = (unsigned long long*)carve((size_t)N_NODES * 8);
    float* pp   = (float*)carve((size_t)PSLOTS * G_GRAPHS * 4);
    char*  zero_end = w + o;                      // packed + pp span
    int*      cnt  = (int*)     carve((size_t)N_NODES * 4);
    float*    dinv = (float*)   carve((size_t)N_NODES * 4);
    int*      offs = (int*)     carve((size_t)N_NODES * 4);
    int*      part = (int*)     carve(64 * 4);
    uint16_t* seq  = (uint16_t*)carve((size_t)N_EDGES * 2);
    int2*     csr  = (int2*)    carve((size_t)NTOT * 8);
    uint32_t* tA   = (uint32_t*)carve((size_t)N_NODES * 128);     // fp8 rows
    uint32_t* tB   = (uint32_t*)carve((size_t)N_NODES * 128);     // fp8 rows
    uint16_t* wsz  = (uint16_t*)carve((size_t)2 * 16384 * 2);     // frag-order W2,W3
    (void)ws_size; (void)in_sizes; (void)n_in; (void)out_size;

    hipMemsetAsync(packed, 0, (size_t)(zero_end - (char*)packed), stream);

    k_wswz<<<128, 256, 0, stream>>>(W2, W3, wsz);
    // fused: edge histogram (atomic-bound) + layer-1 transform (MFMA-bound)
    k_deg_transform<<<NTB + NDB, 256, 0, stream>>>(ei, ew, packed, seq, x, W1, tA);
    k_scan1<<<SCAN_NB, 256, 0, stream>>>(packed, cnt, dinv, part);
    k_scan3<<<SCAN_NB, 256, 0, stream>>>(cnt, part, offs);
    k_fill<<<(NTOT + 255) / 256, 256, 0, stream>>>(ei, ew, dinv, offs, cnt, seq, csr);

    // fused aggregate+transform per layer boundary (h never leaves LDS)
    k_agg_tr<<<NSTRIPS, 256, 0, stream>>>(tA, offs, cnt, csr, b1,
                                          (const bf16x8*)wsz, tB);
    k_agg_tr<<<NSTRIPS, 256, 0, stream>>>(tB, offs, cnt, csr, b2,
                                          (const bf16x8*)(wsz + 16384), tA);
    k_agg_pool<<<NSTRIPS, 256, 0, stream>>>(tA, offs, cnt, csr, b3, lw, bat, pp);

    k_final<<<1, G_GRAPHS, 0, stream>>>(pp, bat, lb, out);
}